// Round 10
// baseline (9192.525 us; speedup 1.0000x reference)
//
#include <hip/hip_runtime.h>

// Seq2Seq LSTM H=128: enc 8192 + dec 4096 strictly sequential steps.
// Main block on one CU, 512 threads (8 waves). ONE barrier per step.
// Body = R9/R7 (9.09 ms): pk_fma matvec over j-pairs, DPP quad_perm gate
// gather, h via producing-quad readlane, partials double-buffered
// (parity st&1), partial idx = 5u+g, per-gate nonlin before gather,
// decoder fc folded into Whh, out piggybacked on wave 7.
// R10 changes (only):
//  1. Decoder outputs buffered in LDS, flushed once at the end.
//     __syncthreads drains vmcnt(0) (m97 asm evidence) -> the per-step
//     global_store made every decoder barrier wait for an HBM write-ack
//     (~400-900 cyc). Removing all VM ops from the loop frees the barrier.
//  2. Partial reduce uses a 3-deep add tree instead of an 8-deep chain.
// Heaters identical to R9 (continuous pk_fma, 1 wave/CU) for attribution.

#define H      128
#define ENC_T  8192
#define DEC_T  4096
#define NT     512
#define NBLK   256
#define MAGIC  0xC0FFEEu
#define PSLICE 648          // floats per slice stride; idx = 5u+g <= 638

typedef float v2f __attribute__((ext_vector_type(2)));

__device__ __forceinline__ v2f pk_fma(v2f a, v2f b, v2f c) {
    v2f d;
    asm("v_pk_fma_f32 %0, %1, %2, %3" : "=v"(d) : "v"(a), "v"(b), "v"(c));
    return d;
}
__device__ __forceinline__ float sigm(float x) {
    return __builtin_amdgcn_rcpf(1.0f + __expf(-x));   // exact at +-inf
}
__device__ __forceinline__ float tanhfast(float x) {
    return 1.0f - 2.0f * __builtin_amdgcn_rcpf(1.0f + __expf(2.0f * x));
}
__device__ __forceinline__ float rdlane(float v, int l) {
    return __int_as_float(__builtin_amdgcn_readlane(__float_as_int(v), l));
}
template <int CTRL>
__device__ __forceinline__ float qperm(float v) {      // DPP quad_perm, VALU-speed
    return __int_as_float(
        __builtin_amdgcn_mov_dpp(__float_as_int(v), CTRL, 0xf, 0xf, true));
}

__global__ __launch_bounds__(NT, 2)
void seq2seq_lstm(const float* __restrict__ input_seq,
                  const float* __restrict__ enc_Wih,
                  const float* __restrict__ enc_Whh,
                  const float* __restrict__ enc_bih,
                  const float* __restrict__ enc_bhh,
                  const float* __restrict__ dec_Wih,
                  const float* __restrict__ dec_Whh,
                  const float* __restrict__ dec_bih,
                  const float* __restrict__ dec_bhh,
                  const float* __restrict__ fc_W,
                  const float* __restrict__ fc_b,
                  float* __restrict__ out,
                  unsigned* __restrict__ wsflag)
{
    // ---- continuous-burn heaters: sustained 1-wave VALU load per CU ----
    if (blockIdx.x != 0) {
        if (threadIdx.x >= 64) return;      // one wave per CU
        v2f z0 = {0.37f, 1.11f}, z1 = {2.03f, 0.55f};
        v2f z2 = {1.77f, 0.91f}, z3 = {0.13f, 2.41f};
        const v2f ka = {1.0009765625f, 0.9990234375f};
        const v2f kb = {1e-7f, 1e-7f};
        for (int it = 0; it < 600000; ++it) {
            unsigned f = 0;
            if (threadIdx.x == 0)
                f = __hip_atomic_load(wsflag, __ATOMIC_RELAXED, __HIP_MEMORY_SCOPE_AGENT);
            f = (unsigned)__shfl((int)f, 0, 64);
            if (f == MAGIC) break;
#pragma unroll
            for (int k = 0; k < 64; ++k) {  // 256 pk_fma ~ 512 cyc burst
                z0 = pk_fma(z0, ka, kb); z1 = pk_fma(z1, ka, kb);
                z2 = pk_fma(z2, ka, kb); z3 = pk_fma(z3, ka, kb);
            }
        }
        if (z0.x + z1.x + z2.x + z3.x == 12345.678f && threadIdx.x == 63)
            wsflag[1] = 7u;                 // unreachable sink
        return;
    }

    // ---- main block ----
    __shared__ __align__(16) float xin[ENC_T];          // 32 KB
    __shared__ __align__(16) float hbuf[2][H];          // h history (off-path)
    __shared__ __align__(16) float part[2][8 * PSLICE]; // dbl-buffered partials
    __shared__ __align__(16) float out_lds[DEC_T];      // 16 KB output stage

    const int t    = threadIdx.x;      // 0..511
    const int lane = t & 63;
    const int wv   = t >> 6;           // wave 0..7, j-slice [16wv,16wv+16)
    const int jb   = 16 * wv;
    const int qq   = lane >> 2;        // reduce role: unit-in-slice 0..15
    const int g    = lane & 3;         // gate 0=i 1=f 2=g 3=o
    const int myu  = jb + qq;          // my unit (global)
    const int myrow = g * H + myu;     // my gate row
    const int prd  = 5 * myu + g;      // partial read idx within a slice
    const int pwb  = wv * PSLICE + 5 * lane;   // partial write base

    {   // stage input sequence
        const float4* s = (const float4*)input_seq;
        float4* d = (float4*)xin;
        for (int i = t; i < ENC_T / 4; i += NT) d[i] = s[i];
    }

    // matvec weights as j-pairs: w2[s][jj] = Whh[(64s+lane)][jb+2jj, jb+2jj+1]
    v2f w2[8][8];
#pragma unroll
    for (int s = 0; s < 8; ++s) {
        const v2f* Wr = (const v2f*)(enc_Whh + (64 * s + lane) * H + jb);
#pragma unroll
        for (int jj = 0; jj < 8; ++jj) w2[s][jj] = Wr[jj];
    }
    float bias_r = enc_bih[myrow] + enc_bhh[myrow];
    float wih_r  = enc_Wih[myrow];

    float cst = 0.f;      // cell state of unit myu (replicated per quad)
    float hn  = 0.f;      // h of unit myu (replicated per quad)
    __syncthreads();

    // h[jb+2jj+c] lives in quad 2jj+c of this wave -> g==3 lane 8jj+4c+3
#define MATVEC(PB)                                                          \
    {                                                                       \
        v2f acc2[8];                                                        \
        _Pragma("unroll") for (int s = 0; s < 8; ++s)                       \
            acc2[s] = (v2f){0.f, 0.f};                                      \
        _Pragma("unroll") for (int jj = 0; jj < 8; ++jj) {                  \
            const float se = rdlane(hn, 8 * jj + 3);                        \
            const float so = rdlane(hn, 8 * jj + 7);                        \
            const v2f hp = {se, so};                                        \
            _Pragma("unroll") for (int s = 0; s < 8; ++s)                   \
                acc2[s] = pk_fma(w2[s][jj], hp, acc2[s]);                   \
        }                                                                   \
        /* row 64s+lane -> idx 5*lane + 320*(s&1) + (s>>1), stride-5 */     \
        float* pb_ = &part[PB][pwb];                                        \
        pb_[0]   = acc2[0].x + acc2[0].y; pb_[320] = acc2[1].x + acc2[1].y; \
        pb_[1]   = acc2[2].x + acc2[2].y; pb_[321] = acc2[3].x + acc2[3].y; \
        pb_[2]   = acc2[4].x + acc2[4].y; pb_[322] = acc2[5].x + acc2[5].y; \
        pb_[3]   = acc2[6].x + acc2[6].y; pb_[323] = acc2[7].x + acc2[7].y; \
    }

#define REDUCE_UPDATE(PB, ABASE)                                            \
    {                                                                       \
        const float p0 = part[PB][0 * PSLICE + prd];                        \
        const float p1 = part[PB][1 * PSLICE + prd];                        \
        const float p2 = part[PB][2 * PSLICE + prd];                        \
        const float p3 = part[PB][3 * PSLICE + prd];                        \
        const float p4 = part[PB][4 * PSLICE + prd];                        \
        const float p5 = part[PB][5 * PSLICE + prd];                        \
        const float p6 = part[PB][6 * PSLICE + prd];                        \
        const float p7 = part[PB][7 * PSLICE + prd];                        \
        const float a = (ABASE) +                                           \
            (((p0 + p1) + (p2 + p3)) + ((p4 + p5) + (p6 + p7)));            \
        const float v = (g == 2) ? tanhfast(a) : sigm(a);                   \
        const float vi = qperm<0x00>(v);   /* quad lane 0 */                \
        const float vf = qperm<0x55>(v);   /* quad lane 1 */                \
        const float vg = qperm<0xAA>(v);   /* quad lane 2 */                \
        const float vo = qperm<0xFF>(v);   /* quad lane 3 */                \
        cst = fmaf(vf, cst, vi * vg);                                       \
        hn  = vo * tanhfast(cst);                                           \
        if (g == 3) hbuf[PB][myu] = hn;                                     \
    }

    // ---------------- encoder: 8192 steps, ONE barrier each ----------------
    for (int st = 0; st < ENC_T; ++st) {
        const int pb = st & 1;
        MATVEC(pb);
        const float x = xin[st];
        __syncthreads();
        REDUCE_UPDATE(pb, fmaf(wih_r, x, bias_r));
    }

    // ---------------- decoder setup: fold fc into Whh ----------------
    const float fcb = fc_b[0];
    const float fwl = fc_W[lane];
    const float fwh = fc_W[64 + lane];
#pragma unroll
    for (int s = 0; s < 8; ++s) {
        const int r = 64 * s + lane;
        const float vi = dec_Wih[r];
        const v2f vip = {vi, vi};
        const v2f* Wr = (const v2f*)(dec_Whh + r * H + jb);
        const v2f* Fr = (const v2f*)(fc_W + jb);
#pragma unroll
        for (int jj = 0; jj < 8; ++jj)
            w2[s][jj] = pk_fma(vip, Fr[jj], Wr[jj]);   // W' = Whh + wih (x) fcW
    }
    wih_r  = dec_Wih[myrow];
    bias_r = dec_bih[myrow] + dec_bhh[myrow] + wih_r * fcb;
    __syncthreads();                       // h_enc visible in hbuf[1]
    float q0;
    {
        float p = fmaf(fwl, hbuf[1][lane], fwh * hbuf[1][64 + lane]);
        p += qperm<0xB1>(p);               // xor 1
        p += qperm<0x4E>(p);               // xor 2
#pragma unroll
        for (int m = 32; m >= 4; m >>= 1) p += __shfl_xor(p, m, 64);
        q0 = p + fcb;
    }
    float cb = bias_r - wih_r * q0;        // step-0 correction (y0 = 0)

    // ---------------- decoder: 4096 steps (NO VM ops in loop) --------------
    for (int st = 0; st < DEC_T; ++st) {
        const int pb = st & 1;
        MATVEC(pb);
        if (wv == 7 && st >= 2) {          // out[st-2] from 2-step-stale hbuf
            float p = fmaf(fwl, hbuf[pb][lane], fwh * hbuf[pb][64 + lane]);
            p += qperm<0xB1>(p);
            p += qperm<0x4E>(p);
#pragma unroll
            for (int m = 32; m >= 4; m >>= 1) p += __shfl_xor(p, m, 64);
            if (lane == 0) out_lds[st - 2] = p + fcb;   // LDS, not global
        }
        __syncthreads();
        REDUCE_UPDATE(pb, cb);
        cb = bias_r;
    }

    // tail outputs for steps DEC_T-2 (hbuf[0]) and DEC_T-1 (hbuf[1])
    __syncthreads();
    if (wv == 7) {
        float p0 = fmaf(fwl, hbuf[0][lane], fwh * hbuf[0][64 + lane]);
        float p1 = fmaf(fwl, hbuf[1][lane], fwh * hbuf[1][64 + lane]);
#pragma unroll
        for (int m = 32; m >= 1; m >>= 1) {
            p0 += __shfl_xor(p0, m, 64);
            p1 += __shfl_xor(p1, m, 64);
        }
        if (lane == 0) {
            out_lds[DEC_T - 2] = p0 + fcb;
            out_lds[DEC_T - 1] = p1 + fcb;
        }
    }
    __syncthreads();                       // out_lds complete

    // one coalesced flush of all 4096 outputs
    {
        const float4* s = (const float4*)out_lds;
        float4* d = (float4*)out;
        for (int i = t; i < DEC_T / 4; i += NT) d[i] = s[i];
    }
    if (t == 0)
        __hip_atomic_store(wsflag, MAGIC, __ATOMIC_RELEASE, __HIP_MEMORY_SCOPE_AGENT);
}

extern "C" void kernel_launch(void* const* d_in, const int* in_sizes, int n_in,
                              void* d_out, int out_size, void* d_ws, size_t ws_size,
                              hipStream_t stream)
{
    (void)in_sizes; (void)n_in; (void)ws_size; (void)out_size;
    seq2seq_lstm<<<NBLK, NT, 0, stream>>>(
        (const float*)d_in[0],   // input_seq
        (const float*)d_in[1],   // enc_Wih
        (const float*)d_in[2],   // enc_Whh
        (const float*)d_in[3],   // enc_bih
        (const float*)d_in[4],   // enc_bhh
        (const float*)d_in[5],   // dec_Wih
        (const float*)d_in[6],   // dec_Whh
        (const float*)d_in[7],   // dec_bih
        (const float*)d_in[8],   // dec_bhh
        (const float*)d_in[9],   // fc_W
        (const float*)d_in[10],  // fc_b
        (float*)d_out,
        (unsigned*)d_ws);
}